// Round 1
// baseline (885.581 us; speedup 1.0000x reference)
//
#include <hip/hip_runtime.h>
#include <math.h>

// GATv2 (3 layers) fused: CSR-gather online-softmax attention + bias + residual + LayerNorm + exact GeLU.
// N=100k nodes, D=H*C=64 (one 64-lane wave per node), E=1.28M edges + N self-loops.

#define SCAN_CHUNK 1024

static inline int cdiv(int a, int b) { return (a + b - 1) / b; }

// ---------------- CSR build ----------------

// Detect whether edge_index arrived as int64 (odd 32-bit words all zero) or int32.
__global__ void detect_i64(const unsigned int* __restrict__ ei, int* __restrict__ flag) {
    if (threadIdx.x == 0 && blockIdx.x == 0) {
        int is64 = 1;
        #pragma unroll 1
        for (int i = 0; i < 64; ++i)
            if (ei[2 * i + 1] != 0u) { is64 = 0; break; }
        *flag = is64;
    }
}

__global__ void init_deg(int* __restrict__ deg, int* __restrict__ cursor, int N) {
    int i = blockIdx.x * blockDim.x + threadIdx.x;
    if (i < N) { deg[i] = 1; cursor[i] = 0; }  // deg starts at 1: self-loop
}

__global__ void hist_kernel(const int* __restrict__ ei, int E, const int* __restrict__ flag,
                            int* __restrict__ deg) {
    int e = blockIdx.x * blockDim.x + threadIdx.x;
    if (e >= E) return;
    int is64 = *flag;
    int d = is64 ? ei[2 * (E + e)] : ei[E + e];  // int64 little-endian: low word holds value
    atomicAdd(&deg[d], 1);
}

__global__ void scan_blocks(const int* __restrict__ deg, int* __restrict__ rowptr,
                            int* __restrict__ partials, int N) {
    __shared__ int sdata[256];
    int t = threadIdx.x;
    int idx0 = blockIdx.x * SCAN_CHUNK + t * 4;
    int v[4]; int sum = 0;
    #pragma unroll
    for (int i = 0; i < 4; ++i) {
        int ii = idx0 + i;
        v[i] = (ii < N) ? deg[ii] : 0;
        sum += v[i];
    }
    sdata[t] = sum;
    __syncthreads();
    for (int off = 1; off < 256; off <<= 1) {   // inclusive Hillis-Steele
        int val = 0;
        if (t >= off) val = sdata[t - off];
        __syncthreads();
        if (t >= off) sdata[t] += val;
        __syncthreads();
    }
    int run = (t > 0) ? sdata[t - 1] : 0;       // block-local exclusive
    #pragma unroll
    for (int i = 0; i < 4; ++i) {
        int ii = idx0 + i;
        if (ii < N) rowptr[ii] = run;
        run += v[i];
    }
    if (t == 255) partials[blockIdx.x] = sdata[255];
}

__global__ void scan_partials_k(int* __restrict__ partials, int NB) {
    __shared__ int sd[256];
    int t = threadIdx.x;
    sd[t] = (t < NB) ? partials[t] : 0;
    __syncthreads();
    for (int off = 1; off < 256; off <<= 1) {
        int val = 0;
        if (t >= off) val = sd[t - off];
        __syncthreads();
        if (t >= off) sd[t] += val;
        __syncthreads();
    }
    if (t < NB) partials[t] = (t > 0) ? sd[t - 1] : 0;  // exclusive
}

__global__ void add_offsets(int* __restrict__ rowptr, const int* __restrict__ partials,
                            int N, int Etot) {
    int i = blockIdx.x * blockDim.x + threadIdx.x;
    if (i < N) rowptr[i] += partials[i / SCAN_CHUNK];
    if (i == 0) rowptr[N] = Etot;
}

__global__ void fill_csr(const int* __restrict__ ei, int E, int N, const int* __restrict__ flag,
                         const int* __restrict__ rowptr, int* __restrict__ cursor,
                         int* __restrict__ col) {
    int i = blockIdx.x * blockDim.x + threadIdx.x;
    if (i >= E + N) return;
    int s, d;
    if (i < E) {
        int is64 = *flag;
        s = is64 ? ei[2 * i] : ei[i];
        d = is64 ? ei[2 * (E + i)] : ei[E + i];
    } else {
        s = d = i - E;  // self-loop
    }
    int pos = atomicAdd(&cursor[d], 1);
    col[rowptr[d] + pos] = s;
}

// ---------------- per-layer kernels ----------------

// XL = x @ Wl, XR = x @ Wr.  One wave per node; W staged in LDS; x row broadcast via shfl.
__global__ __launch_bounds__(256) void transform_kernel(
    const float* __restrict__ x, const float* __restrict__ Wl, const float* __restrict__ Wr,
    float* __restrict__ XL, float* __restrict__ XR, int N) {
    __shared__ float sWl[64 * 64];
    __shared__ float sWr[64 * 64];
    for (int i = threadIdx.x; i < 64 * 64; i += blockDim.x) {
        sWl[i] = Wl[i];
        sWr[i] = Wr[i];
    }
    __syncthreads();
    int lane = threadIdx.x & 63;
    int wave = (blockIdx.x * blockDim.x + threadIdx.x) >> 6;
    int nwaves = (gridDim.x * blockDim.x) >> 6;
    for (int n = wave; n < N; n += nwaves) {
        float xv = x[(size_t)n * 64 + lane];
        float accL = 0.f, accR = 0.f;
        #pragma unroll
        for (int k = 0; k < 64; ++k) {
            float xk = __shfl(xv, k);
            accL = fmaf(xk, sWl[k * 64 + lane], accL);
            accR = fmaf(xk, sWr[k * 64 + lane], accR);
        }
        XL[(size_t)n * 64 + lane] = accL;
        XR[(size_t)n * 64 + lane] = accR;
    }
}

// One wave per destination node: online-softmax GATv2 gather, + bias + residual + LN + GeLU.
__global__ __launch_bounds__(256) void gat_gather_kernel(
    const float* __restrict__ XL, const float* __restrict__ XR,
    const float* __restrict__ x_res,
    const int* __restrict__ rowptr, const int* __restrict__ col,
    const float* __restrict__ att, const float* __restrict__ bias,
    const float* __restrict__ gamma, const float* __restrict__ beta,
    float* __restrict__ x_out, int N) {
    int wid = (blockIdx.x * blockDim.x + threadIdx.x) >> 6;
    int lane = threadIdx.x & 63;
    if (wid >= N) return;
    const int n = wid;

    float xr = XR[(size_t)n * 64 + lane];
    float attl = att[lane];                   // att[h][c] flattened == att[lane]
    int start = rowptr[n], end = rowptr[n + 1];

    float m = -INFINITY, s = 0.f, o = 0.f;
    for (int base = start; base < end; base += 64) {
        int rem = end - base;
        int cl = (lane < rem) ? col[base + lane] : 0;
        int cnt = rem < 64 ? rem : 64;
        for (int j = 0; j < cnt; ++j) {
            int srcn = __shfl(cl, j);
            float v = XL[(size_t)srcn * 64 + lane];
            float t = v + xr;
            t = (t > 0.f) ? t : 0.2f * t;     // leaky_relu(0.2)
            float w = t * attl;
            w += __shfl_xor(w, 1);            // 16-lane (per-head) reduce
            w += __shfl_xor(w, 2);
            w += __shfl_xor(w, 4);
            w += __shfl_xor(w, 8);
            float mnew = fmaxf(m, w);
            float p = __expf(w - mnew);
            float scale = __expf(m - mnew);   // exp(-inf)=0 on first edge
            s = fmaf(s, scale, p);
            o = o * scale + p * v;
            m = mnew;
        }
    }

    float g = o / s + bias[lane] + x_res[(size_t)n * 64 + lane];

    // LayerNorm over the 64 lanes
    float mu = g;
    #pragma unroll
    for (int d = 32; d > 0; d >>= 1) mu += __shfl_xor(mu, d);
    mu *= (1.f / 64.f);
    float dv = g - mu;
    float var = dv * dv;
    #pragma unroll
    for (int d = 32; d > 0; d >>= 1) var += __shfl_xor(var, d);
    var *= (1.f / 64.f);
    float y = dv * rsqrtf(var + 1e-5f) * gamma[lane] + beta[lane];

    // exact GeLU
    float outv = 0.5f * y * (1.f + erff(y * 0.70710678118654752f));
    x_out[(size_t)n * 64 + lane] = outv;
}

// ---------------- launch ----------------

extern "C" void kernel_launch(void* const* d_in, const int* in_sizes, int n_in,
                              void* d_out, int out_size, void* d_ws, size_t ws_size,
                              hipStream_t stream) {
    const float* x0    = (const float*)d_in[0];
    const int*   ei    = (const int*)d_in[1];
    const float* Wl    = (const float*)d_in[2];
    const float* Wr    = (const float*)d_in[3];
    const float* att   = (const float*)d_in[4];
    const float* bias  = (const float*)d_in[5];
    const float* gamma = (const float*)d_in[6];
    const float* beta  = (const float*)d_in[7];
    float* out = (float*)d_out;

    const int N = in_sizes[0] / 64;
    const int E = in_sizes[1] / 2;
    const int Lnum = in_sizes[2] / (64 * 64);
    const int Etot = E + N;

    char* ws = (char*)d_ws;
    size_t off = 0;
    auto alloc = [&](size_t bytes) {
        void* p = ws + off;
        off = (off + bytes + 255) & ~(size_t)255;
        return p;
    };
    float* XL     = (float*)alloc((size_t)N * 64 * 4);
    float* XR     = (float*)alloc((size_t)N * 64 * 4);
    float* XA     = (float*)alloc((size_t)N * 64 * 4);
    int* rowptr   = (int*)alloc((size_t)(N + 1) * 4);
    int* deg      = (int*)alloc((size_t)N * 4);
    int* cursor   = (int*)alloc((size_t)N * 4);
    int* partials = (int*)alloc(1024 * 4);
    int* flag     = (int*)alloc(256);
    int* col      = (int*)alloc((size_t)Etot * 4);

    // CSR build (graph is static across layers)
    detect_i64<<<1, 64, 0, stream>>>((const unsigned int*)ei, flag);
    init_deg<<<cdiv(N, 256), 256, 0, stream>>>(deg, cursor, N);
    hist_kernel<<<cdiv(E, 256), 256, 0, stream>>>(ei, E, flag, deg);
    int NB = cdiv(N, SCAN_CHUNK);
    scan_blocks<<<NB, 256, 0, stream>>>(deg, rowptr, partials, N);
    scan_partials_k<<<1, 256, 0, stream>>>(partials, NB);
    add_offsets<<<cdiv(N + 1, 256), 256, 0, stream>>>(rowptr, partials, N, Etot);
    fill_csr<<<cdiv(Etot, 256), 256, 0, stream>>>(ei, E, N, flag, rowptr, cursor, col);

    const float* xcur = x0;
    for (int l = 0; l < Lnum; ++l) {
        const float* Wl_l = Wl + (size_t)l * 64 * 64;
        const float* Wr_l = Wr + (size_t)l * 64 * 64;
        transform_kernel<<<2048, 256, 0, stream>>>(xcur, Wl_l, Wr_l, XL, XR, N);
        float* xnext = (l == Lnum - 1) ? out : XA;  // in-place on XA is safe: each wave
                                                    // touches only its own row of x_res
        gat_gather_kernel<<<cdiv(N * 64, 256), 256, 0, stream>>>(
            XL, XR, xcur, rowptr, col,
            att + (size_t)l * 64, bias + (size_t)l * 64,
            gamma + (size_t)l * 64, beta + (size_t)l * 64,
            xnext, N);
        xcur = xnext;
    }
}

// Round 2
// 662.853 us; speedup vs baseline: 1.3360x; 1.3360x over previous
//
#include <hip/hip_runtime.h>
#include <math.h>

// GATv2 (3 layers): CSR gather + online-softmax attention + bias + residual + LN + exact GeLU.
// N=100k, D=H*C=64, E=1.28M (+N self-loops). One 64-lane wave per node in the gather;
// lane = (edge_slot g = lane>>4) x (feature_quad c = lane&15): 4 edges in flight per wave,
// each lane owns 4 contiguous features (one head per 4-lane quad). XL stored bf16.

#define SCAN_CHUNK 1024

static inline int cdiv(int a, int b) { return (a + b - 1) / b; }

// ---------------- CSR build ----------------

__global__ void detect_i64(const unsigned int* __restrict__ ei, int* __restrict__ flag) {
    if (threadIdx.x == 0 && blockIdx.x == 0) {
        int is64 = 1;
        #pragma unroll 1
        for (int i = 0; i < 64; ++i)
            if (ei[2 * i + 1] != 0u) { is64 = 0; break; }
        *flag = is64;
    }
}

__global__ void init_deg(int* __restrict__ deg, int N) {
    int i = blockIdx.x * blockDim.x + threadIdx.x;
    if (i < N) deg[i] = 1;  // self-loop occupies slot 0
}

// Histogram + record each edge's slot within its destination row (no 2nd atomic pass).
__global__ void hist_kernel(const int* __restrict__ ei, int E, const int* __restrict__ flag,
                            int* __restrict__ deg, int* __restrict__ pos) {
    int e = blockIdx.x * blockDim.x + threadIdx.x;
    if (e >= E) return;
    int is64 = *flag;
    int d = is64 ? ei[2 * (E + e)] : ei[E + e];
    pos[e] = atomicAdd(&deg[d], 1);
}

__global__ void scan_blocks(const int* __restrict__ deg, int* __restrict__ rowptr,
                            int* __restrict__ partials, int N) {
    __shared__ int sdata[256];
    int t = threadIdx.x;
    int idx0 = blockIdx.x * SCAN_CHUNK + t * 4;
    int v[4]; int sum = 0;
    #pragma unroll
    for (int i = 0; i < 4; ++i) {
        int ii = idx0 + i;
        v[i] = (ii < N) ? deg[ii] : 0;
        sum += v[i];
    }
    sdata[t] = sum;
    __syncthreads();
    for (int off = 1; off < 256; off <<= 1) {
        int val = 0;
        if (t >= off) val = sdata[t - off];
        __syncthreads();
        if (t >= off) sdata[t] += val;
        __syncthreads();
    }
    int run = (t > 0) ? sdata[t - 1] : 0;
    #pragma unroll
    for (int i = 0; i < 4; ++i) {
        int ii = idx0 + i;
        if (ii < N) rowptr[ii] = run;
        run += v[i];
    }
    if (t == 255) partials[blockIdx.x] = sdata[255];
}

__global__ void scan_partials_k(int* __restrict__ partials, int NB) {
    __shared__ int sd[256];
    int t = threadIdx.x;
    sd[t] = (t < NB) ? partials[t] : 0;
    __syncthreads();
    for (int off = 1; off < 256; off <<= 1) {
        int val = 0;
        if (t >= off) val = sd[t - off];
        __syncthreads();
        if (t >= off) sd[t] += val;
        __syncthreads();
    }
    if (t < NB) partials[t] = (t > 0) ? sd[t - 1] : 0;
}

__global__ void add_offsets(int* __restrict__ rowptr, const int* __restrict__ partials,
                            int N, int Etot) {
    int i = blockIdx.x * blockDim.x + threadIdx.x;
    if (i < N) rowptr[i] += partials[i / SCAN_CHUNK];
    if (i == 0) rowptr[N] = Etot;
}

// Atomic-free CSR fill using precomputed slots.
__global__ void fill_csr(const int* __restrict__ ei, int E, int N, const int* __restrict__ flag,
                         const int* __restrict__ rowptr, const int* __restrict__ pos,
                         int* __restrict__ col) {
    int i = blockIdx.x * blockDim.x + threadIdx.x;
    if (i >= E + N) return;
    if (i < E) {
        int is64 = *flag;
        int s = is64 ? ei[2 * i] : ei[i];
        int d = is64 ? ei[2 * (E + i)] : ei[E + i];
        col[rowptr[d] + pos[i]] = s;
    } else {
        int nn = i - E;
        col[rowptr[nn]] = nn;  // self-loop at slot 0
    }
}

// ---------------- per-layer kernels ----------------

// XL(bf16) = x @ Wl, XR(f32) = x @ Wr. Wave parity selects the matrix; each wave holds its
// 64-row W column slice in VGPRs; x rows arrive as wave-broadcast float4 loads.
__global__ __launch_bounds__(256) void transform_kernel(
    const float* __restrict__ x, const float* __restrict__ Wl, const float* __restrict__ Wr,
    unsigned short* __restrict__ XL, float* __restrict__ XR, int N) {
    int lane = threadIdx.x & 63;
    int wid = (blockIdx.x * blockDim.x + threadIdx.x) >> 6;
    int nw = (gridDim.x * blockDim.x) >> 6;
    int sel = wid & 1;
    const float* __restrict__ W = sel ? Wr : Wl;
    float w[64];
    #pragma unroll
    for (int k = 0; k < 64; ++k) w[k] = W[k * 64 + lane];

    for (int n0 = (wid >> 1) * 2; n0 < N; n0 += nw) {
        int n1 = (n0 + 1 < N) ? n0 + 1 : n0;
        const float4* xr0 = (const float4*)(x + (size_t)n0 * 64);
        const float4* xr1 = (const float4*)(x + (size_t)n1 * 64);
        float a0 = 0.f, a1 = 0.f;
        #pragma unroll
        for (int q = 0; q < 16; ++q) {
            float4 v0 = xr0[q];
            float4 v1 = xr1[q];
            a0 = fmaf(v0.x, w[4 * q + 0], a0);
            a0 = fmaf(v0.y, w[4 * q + 1], a0);
            a0 = fmaf(v0.z, w[4 * q + 2], a0);
            a0 = fmaf(v0.w, w[4 * q + 3], a0);
            a1 = fmaf(v1.x, w[4 * q + 0], a1);
            a1 = fmaf(v1.y, w[4 * q + 1], a1);
            a1 = fmaf(v1.z, w[4 * q + 2], a1);
            a1 = fmaf(v1.w, w[4 * q + 3], a1);
        }
        if (sel) {
            XR[(size_t)n0 * 64 + lane] = a0;
            if (n1 != n0) XR[(size_t)n1 * 64 + lane] = a1;
        } else {
            unsigned u0 = __float_as_uint(a0);
            XL[(size_t)n0 * 64 + lane] = (unsigned short)((u0 + 0x7fffu + ((u0 >> 16) & 1u)) >> 16);
            if (n1 != n0) {
                unsigned u1 = __float_as_uint(a1);
                XL[(size_t)n1 * 64 + lane] = (unsigned short)((u1 + 0x7fffu + ((u1 >> 16) & 1u)) >> 16);
            }
        }
    }
}

// One wave per destination node; 4 edges in flight (subgroups), lane-local per-head
// online softmax; fused bias + residual + LayerNorm + exact GeLU.
__global__ __launch_bounds__(256) void gat_gather_kernel(
    const unsigned short* __restrict__ XL, const float* __restrict__ XR,
    const float* __restrict__ x_res,
    const int* __restrict__ rowptr, const int* __restrict__ col,
    const float* __restrict__ att, const float* __restrict__ bias,
    const float* __restrict__ gamma, const float* __restrict__ beta,
    float* __restrict__ x_out, int N) {
    int wid = (blockIdx.x * blockDim.x + threadIdx.x) >> 6;
    if (wid >= N) return;
    int lane = threadIdx.x & 63;
    int g = lane >> 4;    // edge slot 0..3
    int c = lane & 15;    // feature quad: features 4c..4c+3 (head = c>>2)
    const int n = wid;

    float4 xr = ((const float4*)(XR + (size_t)n * 64))[c];
    float4 av = ((const float4*)att)[c];
    int start = rowptr[n], end = rowptr[n + 1];
    const ushort4* XL4 = (const ushort4*)XL;

    float m = -1e30f, s = 0.f;
    float o0 = 0.f, o1 = 0.f, o2 = 0.f, o3 = 0.f;

    for (int base = start; base < end; base += 64) {
        int rem = end - base;
        int chunk = rem < 64 ? rem : 64;
        int cidx = base + lane;
        int cl = col[cidx < end ? cidx : end - 1];
        int iters = (chunk + 3) >> 2;
        for (int t = 0; t < iters; ++t) {
            int idx = 4 * t + g;
            int srcn = __shfl(cl, idx);
            ushort4 hv = XL4[(size_t)srcn * 16 + c];
            float v0 = __uint_as_float((unsigned)hv.x << 16);
            float v1 = __uint_as_float((unsigned)hv.y << 16);
            float v2 = __uint_as_float((unsigned)hv.z << 16);
            float v3 = __uint_as_float((unsigned)hv.w << 16);
            float t0 = v0 + xr.x; t0 = fmaxf(t0, 0.2f * t0);  // leaky_relu(0.2)
            float t1 = v1 + xr.y; t1 = fmaxf(t1, 0.2f * t1);
            float t2 = v2 + xr.z; t2 = fmaxf(t2, 0.2f * t2);
            float t3 = v3 + xr.w; t3 = fmaxf(t3, 0.2f * t3);
            float wsum = t0 * av.x;
            wsum = fmaf(t1, av.y, wsum);
            wsum = fmaf(t2, av.z, wsum);
            wsum = fmaf(t3, av.w, wsum);
            wsum += __shfl_xor(wsum, 1);   // 4-lane (per-head) reduce
            wsum += __shfl_xor(wsum, 2);
            wsum = (idx < chunk) ? wsum : -1e30f;  // mask tail edges
            float mnew = fmaxf(m, wsum);
            float p = __expf(wsum - mnew);
            float sc = __expf(m - mnew);
            s = fmaf(s, sc, p);
            o0 = fmaf(o0, sc, p * v0);
            o1 = fmaf(o1, sc, p * v1);
            o2 = fmaf(o2, sc, p * v2);
            o3 = fmaf(o3, sc, p * v3);
            m = mnew;
        }
    }

    // merge the 4 subgroup partials (finite sentinel => exp paths stay NaN-free)
    #pragma unroll
    for (int mask = 16; mask <= 32; mask <<= 1) {
        float m2 = __shfl_xor(m, mask);
        float s2 = __shfl_xor(s, mask);
        float q0 = __shfl_xor(o0, mask);
        float q1 = __shfl_xor(o1, mask);
        float q2 = __shfl_xor(o2, mask);
        float q3 = __shfl_xor(o3, mask);
        float mn = fmaxf(m, m2);
        float sa = __expf(m - mn), sb = __expf(m2 - mn);
        s = s * sa + s2 * sb;
        o0 = o0 * sa + q0 * sb;
        o1 = o1 * sa + q1 * sb;
        o2 = o2 * sa + q2 * sb;
        o3 = o3 * sa + q3 * sb;
        m = mn;
    }

    float inv = 1.f / s;
    float4 bi = ((const float4*)bias)[c];
    float4 rs = ((const float4*)(x_res + (size_t)n * 64))[c];
    float g0 = fmaf(o0, inv, bi.x + rs.x);
    float g1 = fmaf(o1, inv, bi.y + rs.y);
    float g2 = fmaf(o2, inv, bi.z + rs.z);
    float g3 = fmaf(o3, inv, bi.w + rs.w);

    // LayerNorm over 64 features (4 per lane x 16 lanes; subgroups hold identical copies)
    float loc = g0 + g1 + g2 + g3;
    #pragma unroll
    for (int mask = 1; mask < 16; mask <<= 1) loc += __shfl_xor(loc, mask);
    float mu = loc * (1.f / 64.f);
    float d0 = g0 - mu, d1 = g1 - mu, d2 = g2 - mu, d3 = g3 - mu;
    float vs = d0 * d0 + d1 * d1 + d2 * d2 + d3 * d3;
    #pragma unroll
    for (int mask = 1; mask < 16; mask <<= 1) vs += __shfl_xor(vs, mask);
    float rstd = rsqrtf(vs * (1.f / 64.f) + 1e-5f);
    float4 ga = ((const float4*)gamma)[c];
    float4 be = ((const float4*)beta)[c];
    float y0 = fmaf(d0 * rstd, ga.x, be.x);
    float y1 = fmaf(d1 * rstd, ga.y, be.y);
    float y2 = fmaf(d2 * rstd, ga.z, be.z);
    float y3 = fmaf(d3 * rstd, ga.w, be.w);

    const float k = 0.70710678118654752f;
    float z0 = 0.5f * y0 * (1.f + erff(y0 * k));
    float z1 = 0.5f * y1 * (1.f + erff(y1 * k));
    float z2 = 0.5f * y2 * (1.f + erff(y2 * k));
    float z3 = 0.5f * y3 * (1.f + erff(y3 * k));

    if (g == 0) {
        float4 outv = make_float4(z0, z1, z2, z3);
        ((float4*)(x_out + (size_t)n * 64))[c] = outv;
    }
}

// ---------------- launch ----------------

extern "C" void kernel_launch(void* const* d_in, const int* in_sizes, int n_in,
                              void* d_out, int out_size, void* d_ws, size_t ws_size,
                              hipStream_t stream) {
    const float* x0    = (const float*)d_in[0];
    const int*   ei    = (const int*)d_in[1];
    const float* Wl    = (const float*)d_in[2];
    const float* Wr    = (const float*)d_in[3];
    const float* att   = (const float*)d_in[4];
    const float* bias  = (const float*)d_in[5];
    const float* gamma = (const float*)d_in[6];
    const float* beta  = (const float*)d_in[7];
    float* out = (float*)d_out;

    const int N = in_sizes[0] / 64;
    const int E = in_sizes[1] / 2;
    const int Lnum = in_sizes[2] / (64 * 64);
    const int Etot = E + N;

    char* ws = (char*)d_ws;
    size_t off = 0;
    auto alloc = [&](size_t bytes) {
        void* p = ws + off;
        off = (off + bytes + 255) & ~(size_t)255;
        return p;
    };
    unsigned short* XLb = (unsigned short*)alloc((size_t)N * 64 * 2);
    float* XR     = (float*)alloc((size_t)N * 64 * 4);
    float* XA     = (float*)alloc((size_t)N * 64 * 4);
    int* rowptr   = (int*)alloc((size_t)(N + 1) * 4);
    int* deg      = (int*)alloc((size_t)N * 4);
    int* pos      = (int*)alloc((size_t)E * 4);
    int* partials = (int*)alloc(1024 * 4);
    int* flag     = (int*)alloc(256);
    int* col      = (int*)alloc((size_t)Etot * 4);

    // CSR build (graph static across layers)
    detect_i64<<<1, 64, 0, stream>>>((const unsigned int*)ei, flag);
    init_deg<<<cdiv(N, 256), 256, 0, stream>>>(deg, N);
    hist_kernel<<<cdiv(E, 256), 256, 0, stream>>>(ei, E, flag, deg, pos);
    int NB = cdiv(N, SCAN_CHUNK);
    scan_blocks<<<NB, 256, 0, stream>>>(deg, rowptr, partials, N);
    scan_partials_k<<<1, 256, 0, stream>>>(partials, NB);
    add_offsets<<<cdiv(N + 1, 256), 256, 0, stream>>>(rowptr, partials, N, Etot);
    fill_csr<<<cdiv(Etot, 256), 256, 0, stream>>>(ei, E, N, flag, rowptr, pos, col);

    const float* xcur = x0;
    for (int l = 0; l < Lnum; ++l) {
        const float* Wl_l = Wl + (size_t)l * 64 * 64;
        const float* Wr_l = Wr + (size_t)l * 64 * 64;
        transform_kernel<<<2048, 256, 0, stream>>>(xcur, Wl_l, Wr_l, XLb, XR, N);
        float* xnext = (l == Lnum - 1) ? out : XA;
        gat_gather_kernel<<<cdiv(N * 64, 256), 256, 0, stream>>>(
            XLb, XR, xcur, rowptr, col,
            att + (size_t)l * 64, bias + (size_t)l * 64,
            gamma + (size_t)l * 64, beta + (size_t)l * 64,
            xnext, N);
        xcur = xnext;
    }
}

// Round 3
// 437.829 us; speedup vs baseline: 2.0227x; 1.5140x over previous
//
#include <hip/hip_runtime.h>
#include <math.h>

// GATv2 (3 layers): bf16x3-split MFMA transform + CSR gather online-softmax attention
// + bias + residual + LayerNorm + exact GeLU.
// N=100k, D=H*C=64, E=1.28M (+N self-loops).

#define SCAN_CHUNK 1024

typedef __attribute__((ext_vector_type(8))) short short8;
typedef __attribute__((ext_vector_type(4))) float f32x4;

static inline int cdiv(int a, int b) { return (a + b - 1) / b; }

__device__ __forceinline__ unsigned short bf16_rtn(float v) {
    unsigned u = __float_as_uint(v);
    return (unsigned short)((u + 0x7fffu + ((u >> 16) & 1u)) >> 16);
}

// ---------------- CSR build ----------------

__global__ void detect_i64(const unsigned int* __restrict__ ei, int* __restrict__ flag) {
    if (threadIdx.x == 0 && blockIdx.x == 0) {
        int is64 = 1;
        #pragma unroll 1
        for (int i = 0; i < 64; ++i)
            if (ei[2 * i + 1] != 0u) { is64 = 0; break; }
        *flag = is64;
    }
}

__global__ void init_deg(int* __restrict__ deg, int N) {
    int i = blockIdx.x * blockDim.x + threadIdx.x;
    if (i < N) deg[i] = 1;  // self-loop occupies slot 0
}

__global__ void hist_kernel(const int* __restrict__ ei, int E, const int* __restrict__ flag,
                            int* __restrict__ deg, int* __restrict__ pos) {
    int e = blockIdx.x * blockDim.x + threadIdx.x;
    if (e >= E) return;
    int is64 = *flag;
    int d = is64 ? ei[2 * (E + e)] : ei[E + e];
    pos[e] = atomicAdd(&deg[d], 1);
}

__global__ void scan_blocks(const int* __restrict__ deg, int* __restrict__ rowptr,
                            int* __restrict__ partials, int N) {
    __shared__ int sdata[256];
    int t = threadIdx.x;
    int idx0 = blockIdx.x * SCAN_CHUNK + t * 4;
    int v[4]; int sum = 0;
    #pragma unroll
    for (int i = 0; i < 4; ++i) {
        int ii = idx0 + i;
        v[i] = (ii < N) ? deg[ii] : 0;
        sum += v[i];
    }
    sdata[t] = sum;
    __syncthreads();
    for (int off = 1; off < 256; off <<= 1) {
        int val = 0;
        if (t >= off) val = sdata[t - off];
        __syncthreads();
        if (t >= off) sdata[t] += val;
        __syncthreads();
    }
    int run = (t > 0) ? sdata[t - 1] : 0;
    #pragma unroll
    for (int i = 0; i < 4; ++i) {
        int ii = idx0 + i;
        if (ii < N) rowptr[ii] = run;
        run += v[i];
    }
    if (t == 255) partials[blockIdx.x] = sdata[255];
}

__global__ void scan_partials_k(int* __restrict__ partials, int NB) {
    __shared__ int sd[256];
    int t = threadIdx.x;
    sd[t] = (t < NB) ? partials[t] : 0;
    __syncthreads();
    for (int off = 1; off < 256; off <<= 1) {
        int val = 0;
        if (t >= off) val = sd[t - off];
        __syncthreads();
        if (t >= off) sd[t] += val;
        __syncthreads();
    }
    if (t < NB) partials[t] = (t > 0) ? sd[t - 1] : 0;
}

__global__ void add_offsets(int* __restrict__ rowptr, const int* __restrict__ partials,
                            int N, int Etot) {
    int i = blockIdx.x * blockDim.x + threadIdx.x;
    if (i < N) rowptr[i] += partials[i / SCAN_CHUNK];
    if (i == 0) rowptr[N] = Etot;
}

__global__ void fill_csr(const int* __restrict__ ei, int E, int N, const int* __restrict__ flag,
                         const int* __restrict__ rowptr, const int* __restrict__ pos,
                         int* __restrict__ col) {
    int i = blockIdx.x * blockDim.x + threadIdx.x;
    if (i >= E + N) return;
    if (i < E) {
        int is64 = *flag;
        int s = is64 ? ei[2 * i] : ei[i];
        int d = is64 ? ei[2 * (E + i)] : ei[E + i];
        col[rowptr[d] + pos[i]] = s;
    } else {
        int nn = i - E;
        col[rowptr[nn]] = nn;  // self-loop at slot 0
    }
}

// ---------------- bf16 hi/lo split helpers ----------------

// x (f32) -> hi, lo bf16 pair, vectorized by 4.
__global__ __launch_bounds__(256) void cast_hi_lo(
    const float* __restrict__ x, unsigned short* __restrict__ hi,
    unsigned short* __restrict__ lo, int total4) {
    int i = blockIdx.x * blockDim.x + threadIdx.x;
    int stride = gridDim.x * blockDim.x;
    for (; i < total4; i += stride) {
        float4 v = ((const float4*)x)[i];
        ushort4 h, l;
        h.x = bf16_rtn(v.x); l.x = bf16_rtn(v.x - __uint_as_float((unsigned)h.x << 16));
        h.y = bf16_rtn(v.y); l.y = bf16_rtn(v.y - __uint_as_float((unsigned)h.y << 16));
        h.z = bf16_rtn(v.z); l.z = bf16_rtn(v.z - __uint_as_float((unsigned)h.z << 16));
        h.w = bf16_rtn(v.w); l.w = bf16_rtn(v.w - __uint_as_float((unsigned)h.w << 16));
        ((ushort4*)hi)[i] = h;
        ((ushort4*)lo)[i] = l;
    }
}

// Pre-swizzle [Wl|Wr] (all layers) into MFMA B-fragment order, bf16 hi/lo.
// Flat index: ((((l*2+h)*4+ct)*2+kc)*64+lane)*8+j  ->  W[k=kc*32+(lane>>4)*8+j][ct*16+(lane&15)]
__global__ void wprep_kernel(const float* __restrict__ Wl, const float* __restrict__ Wr,
                             unsigned short* __restrict__ Bh, unsigned short* __restrict__ Bl,
                             int Lnum) {
    int t = blockIdx.x * blockDim.x + threadIdx.x;
    int total = Lnum * 2 * 4 * 2 * 64 * 8;
    if (t >= total) return;
    int j    = t & 7;
    int lane = (t >> 3) & 63;
    int kc   = (t >> 9) & 1;
    int ct   = (t >> 10) & 3;
    int h    = (t >> 12) & 1;
    int l    = t >> 13;
    const float* W = (h ? Wr : Wl) + (size_t)l * 4096;
    int k = kc * 32 + (lane >> 4) * 8 + j;
    int c = ct * 16 + (lane & 15);
    float v = W[k * 64 + c];
    unsigned short hv = bf16_rtn(v);
    Bh[t] = hv;
    Bl[t] = bf16_rtn(v - __uint_as_float((unsigned)hv << 16));
}

// ---------------- transform: [XL|XR] = x @ [Wl|Wr] via bf16x3 MFMA ----------------
// Wave = one 16-node group x one 64-col half (half 0 -> XL bf16, half 1 -> XR f32).
__global__ __launch_bounds__(256) void transform_mfma(
    const unsigned short* __restrict__ xh, const unsigned short* __restrict__ xlo,
    const unsigned short* __restrict__ Bh, const unsigned short* __restrict__ Bl,
    unsigned short* __restrict__ XL, float* __restrict__ XR, int N) {
    int lane = threadIdx.x & 63;
    int wid = (blockIdx.x * blockDim.x + threadIdx.x) >> 6;
    int nw = (gridDim.x * blockDim.x) >> 6;
    int half = wid & 1;

    const short8* Bh8 = (const short8*)Bh;
    const short8* Bl8 = (const short8*)Bl;
    short8 bh[4][2], bl[4][2];
    #pragma unroll
    for (int ct = 0; ct < 4; ++ct)
        #pragma unroll
        for (int kc = 0; kc < 2; ++kc) {
            int idx = ((half * 4 + ct) * 2 + kc) * 64 + lane;
            bh[ct][kc] = Bh8[idx];
            bl[ct][kc] = Bl8[idx];
        }

    const short8* Ah8 = (const short8*)xh;
    const short8* Al8 = (const short8*)xlo;
    int r16 = lane & 15, kq = lane >> 4;
    int ngroups = N >> 4;  // 100000/16 = 6250 exactly

    for (int gidx = wid >> 1; gidx < ngroups; gidx += (nw >> 1)) {
        int n0 = gidx << 4;
        size_t abase = (size_t)(n0 + r16) * 8 + kq;
        short8 ah0 = Ah8[abase],     ah1 = Ah8[abase + 4];
        short8 al0 = Al8[abase],     al1 = Al8[abase + 4];
        f32x4 acc[4] = {};
        #pragma unroll
        for (int ct = 0; ct < 4; ++ct) {
            acc[ct] = __builtin_amdgcn_mfma_f32_16x16x32_bf16(ah0, bh[ct][0], acc[ct], 0, 0, 0);
            acc[ct] = __builtin_amdgcn_mfma_f32_16x16x32_bf16(ah1, bh[ct][1], acc[ct], 0, 0, 0);
            acc[ct] = __builtin_amdgcn_mfma_f32_16x16x32_bf16(al0, bh[ct][0], acc[ct], 0, 0, 0);
            acc[ct] = __builtin_amdgcn_mfma_f32_16x16x32_bf16(al1, bh[ct][1], acc[ct], 0, 0, 0);
            acc[ct] = __builtin_amdgcn_mfma_f32_16x16x32_bf16(ah0, bl[ct][0], acc[ct], 0, 0, 0);
            acc[ct] = __builtin_amdgcn_mfma_f32_16x16x32_bf16(ah1, bl[ct][1], acc[ct], 0, 0, 0);
        }
        // C/D layout (m89-verified): col = lane&15, row = (lane>>4)*4 + reg
        if (half) {
            #pragma unroll
            for (int ct = 0; ct < 4; ++ct)
                #pragma unroll
                for (int r = 0; r < 4; ++r)
                    XR[(size_t)(n0 + kq * 4 + r) * 64 + ct * 16 + r16] = acc[ct][r];
        } else {
            #pragma unroll
            for (int ct = 0; ct < 4; ++ct)
                #pragma unroll
                for (int r = 0; r < 4; ++r)
                    XL[(size_t)(n0 + kq * 4 + r) * 64 + ct * 16 + r16] = bf16_rtn(acc[ct][r]);
        }
    }
}

// ---------------- gather: online-softmax attention + epilogue ----------------
// One wave per destination node; lane = (edge slot g = lane>>4) x (feature quad c = lane&15).
__global__ __launch_bounds__(256) void gat_gather_kernel(
    const unsigned short* __restrict__ XL, const float* __restrict__ XR,
    const float* __restrict__ x_res,
    const int* __restrict__ rowptr, const int* __restrict__ col,
    const float* __restrict__ att, const float* __restrict__ bias,
    const float* __restrict__ gamma, const float* __restrict__ beta,
    float* __restrict__ x_out,
    unsigned short* __restrict__ xh_out, unsigned short* __restrict__ xlo_out, int N) {
    int wid = (blockIdx.x * blockDim.x + threadIdx.x) >> 6;
    if (wid >= N) return;
    int lane = threadIdx.x & 63;
    int g = lane >> 4;
    int c = lane & 15;
    const int n = wid;

    float4 xr = ((const float4*)(XR + (size_t)n * 64))[c];
    float4 av = ((const float4*)att)[c];
    int start = rowptr[n], end = rowptr[n + 1];
    const ushort4* XL4 = (const ushort4*)XL;

    float m = -1e30f, s = 0.f;
    float o0 = 0.f, o1 = 0.f, o2 = 0.f, o3 = 0.f;

    for (int base = start; base < end; base += 64) {
        int rem = end - base;
        int chunk = rem < 64 ? rem : 64;
        int cidx = base + lane;
        int cl = col[cidx < end ? cidx : end - 1];
        int iters = (chunk + 3) >> 2;
        for (int t = 0; t < iters; ++t) {
            int idx = 4 * t + g;
            int srcn = __shfl(cl, idx);
            ushort4 hv = XL4[(size_t)srcn * 16 + c];
            float v0 = __uint_as_float((unsigned)hv.x << 16);
            float v1 = __uint_as_float((unsigned)hv.y << 16);
            float v2 = __uint_as_float((unsigned)hv.z << 16);
            float v3 = __uint_as_float((unsigned)hv.w << 16);
            float t0 = v0 + xr.x; t0 = fmaxf(t0, 0.2f * t0);
            float t1 = v1 + xr.y; t1 = fmaxf(t1, 0.2f * t1);
            float t2 = v2 + xr.z; t2 = fmaxf(t2, 0.2f * t2);
            float t3 = v3 + xr.w; t3 = fmaxf(t3, 0.2f * t3);
            float wsum = t0 * av.x;
            wsum = fmaf(t1, av.y, wsum);
            wsum = fmaf(t2, av.z, wsum);
            wsum = fmaf(t3, av.w, wsum);
            wsum += __shfl_xor(wsum, 1);
            wsum += __shfl_xor(wsum, 2);
            wsum = (idx < chunk) ? wsum : -1e30f;
            float mnew = fmaxf(m, wsum);
            float p = __expf(wsum - mnew);
            float sc = __expf(m - mnew);
            s = fmaf(s, sc, p);
            o0 = fmaf(o0, sc, p * v0);
            o1 = fmaf(o1, sc, p * v1);
            o2 = fmaf(o2, sc, p * v2);
            o3 = fmaf(o3, sc, p * v3);
            m = mnew;
        }
    }

    #pragma unroll
    for (int mask = 16; mask <= 32; mask <<= 1) {
        float m2 = __shfl_xor(m, mask);
        float s2 = __shfl_xor(s, mask);
        float q0 = __shfl_xor(o0, mask);
        float q1 = __shfl_xor(o1, mask);
        float q2 = __shfl_xor(o2, mask);
        float q3 = __shfl_xor(o3, mask);
        float mn = fmaxf(m, m2);
        float sa = __expf(m - mn), sb = __expf(m2 - mn);
        s = s * sa + s2 * sb;
        o0 = o0 * sa + q0 * sb;
        o1 = o1 * sa + q1 * sb;
        o2 = o2 * sa + q2 * sb;
        o3 = o3 * sa + q3 * sb;
        m = mn;
    }

    float inv = 1.f / s;
    float4 bi = ((const float4*)bias)[c];
    float4 rs = ((const float4*)(x_res + (size_t)n * 64))[c];
    float g0 = fmaf(o0, inv, bi.x + rs.x);
    float g1 = fmaf(o1, inv, bi.y + rs.y);
    float g2 = fmaf(o2, inv, bi.z + rs.z);
    float g3 = fmaf(o3, inv, bi.w + rs.w);

    float loc = g0 + g1 + g2 + g3;
    #pragma unroll
    for (int mask = 1; mask < 16; mask <<= 1) loc += __shfl_xor(loc, mask);
    float mu = loc * (1.f / 64.f);
    float d0 = g0 - mu, d1 = g1 - mu, d2 = g2 - mu, d3 = g3 - mu;
    float vs = d0 * d0 + d1 * d1 + d2 * d2 + d3 * d3;
    #pragma unroll
    for (int mask = 1; mask < 16; mask <<= 1) vs += __shfl_xor(vs, mask);
    float rstd = rsqrtf(vs * (1.f / 64.f) + 1e-5f);
    float4 ga = ((const float4*)gamma)[c];
    float4 be = ((const float4*)beta)[c];
    float y0 = fmaf(d0 * rstd, ga.x, be.x);
    float y1 = fmaf(d1 * rstd, ga.y, be.y);
    float y2 = fmaf(d2 * rstd, ga.z, be.z);
    float y3 = fmaf(d3 * rstd, ga.w, be.w);

    const float k = 0.70710678118654752f;
    float z0 = 0.5f * y0 * (1.f + erff(y0 * k));
    float z1 = 0.5f * y1 * (1.f + erff(y1 * k));
    float z2 = 0.5f * y2 * (1.f + erff(y2 * k));
    float z3 = 0.5f * y3 * (1.f + erff(y3 * k));

    if (g == 0) {
        ((float4*)(x_out + (size_t)n * 64))[c] = make_float4(z0, z1, z2, z3);
        if (xh_out) {  // fused hi/lo bf16 cast for next layer's transform
            ushort4 h, l;
            h.x = bf16_rtn(z0); l.x = bf16_rtn(z0 - __uint_as_float((unsigned)h.x << 16));
            h.y = bf16_rtn(z1); l.y = bf16_rtn(z1 - __uint_as_float((unsigned)h.y << 16));
            h.z = bf16_rtn(z2); l.z = bf16_rtn(z2 - __uint_as_float((unsigned)h.z << 16));
            h.w = bf16_rtn(z3); l.w = bf16_rtn(z3 - __uint_as_float((unsigned)h.w << 16));
            ((ushort4*)(xh_out + (size_t)n * 64))[c] = h;
            ((ushort4*)(xlo_out + (size_t)n * 64))[c] = l;
        }
    }
}

// ---------------- launch ----------------

extern "C" void kernel_launch(void* const* d_in, const int* in_sizes, int n_in,
                              void* d_out, int out_size, void* d_ws, size_t ws_size,
                              hipStream_t stream) {
    const float* x0    = (const float*)d_in[0];
    const int*   ei    = (const int*)d_in[1];
    const float* Wl    = (const float*)d_in[2];
    const float* Wr    = (const float*)d_in[3];
    const float* att   = (const float*)d_in[4];
    const float* bias  = (const float*)d_in[5];
    const float* gamma = (const float*)d_in[6];
    const float* beta  = (const float*)d_in[7];
    float* out = (float*)d_out;

    const int N = in_sizes[0] / 64;
    const int E = in_sizes[1] / 2;
    const int Lnum = in_sizes[2] / (64 * 64);
    const int Etot = E + N;

    char* ws = (char*)d_ws;
    size_t off = 0;
    auto alloc = [&](size_t bytes) {
        void* p = ws + off;
        off = (off + bytes + 255) & ~(size_t)255;
        return p;
    };
    unsigned short* XLb = (unsigned short*)alloc((size_t)N * 64 * 2);
    float* XR     = (float*)alloc((size_t)N * 64 * 4);
    float* XA     = (float*)alloc((size_t)N * 64 * 4);
    unsigned short* xh  = (unsigned short*)alloc((size_t)N * 64 * 2);
    unsigned short* xlo = (unsigned short*)alloc((size_t)N * 64 * 2);
    unsigned short* Bh  = (unsigned short*)alloc((size_t)Lnum * 8192 * 2);
    unsigned short* Bl  = (unsigned short*)alloc((size_t)Lnum * 8192 * 2);
    int* rowptr   = (int*)alloc((size_t)(N + 1) * 4);
    int* deg      = (int*)alloc((size_t)N * 4);
    int* pos      = (int*)alloc((size_t)E * 4);
    int* partials = (int*)alloc(1024 * 4);
    int* flag     = (int*)alloc(256);
    int* col      = (int*)alloc((size_t)Etot * 4);

    // input split + weight pre-swizzle
    cast_hi_lo<<<2048, 256, 0, stream>>>(x0, xh, xlo, N * 16);
    wprep_kernel<<<cdiv(Lnum * 8192, 256), 256, 0, stream>>>(Wl, Wr, Bh, Bl, Lnum);

    // CSR build (graph static across layers)
    detect_i64<<<1, 64, 0, stream>>>((const unsigned int*)ei, flag);
    init_deg<<<cdiv(N, 256), 256, 0, stream>>>(deg, N);
    hist_kernel<<<cdiv(E, 256), 256, 0, stream>>>(ei, E, flag, deg, pos);
    int NB = cdiv(N, SCAN_CHUNK);
    scan_blocks<<<NB, 256, 0, stream>>>(deg, rowptr, partials, N);
    scan_partials_k<<<1, 256, 0, stream>>>(partials, NB);
    add_offsets<<<cdiv(N + 1, 256), 256, 0, stream>>>(rowptr, partials, N, Etot);
    fill_csr<<<cdiv(Etot, 256), 256, 0, stream>>>(ei, E, N, flag, rowptr, pos, col);

    const float* xcur = x0;
    for (int l = 0; l < Lnum; ++l) {
        transform_mfma<<<1024, 256, 0, stream>>>(
            xh, xlo, Bh + (size_t)l * 8192, Bl + (size_t)l * 8192, XLb, XR, N);
        float* xnext = (l == Lnum - 1) ? out : XA;
        int last = (l == Lnum - 1);
        gat_gather_kernel<<<cdiv(N * 64, 256), 256, 0, stream>>>(
            XLb, XR, xcur, rowptr, col,
            att + (size_t)l * 64, bias + (size_t)l * 64,
            gamma + (size_t)l * 64, beta + (size_t)l * 64,
            xnext, last ? nullptr : xh, last ? nullptr : xlo, N);
        xcur = xnext;
    }
}

// Round 4
// 415.126 us; speedup vs baseline: 2.1333x; 1.0547x over previous
//
#include <hip/hip_runtime.h>
#include <math.h>

// GATv2 (3 layers): bf16-split MFMA transform + CSR gather online-softmax attention
// + bias + residual + LayerNorm + exact GeLU.
// N=100k, D=H*C=64, E=1.28M (+N self-loops).

#define SCAN_CHUNK 1024

typedef __attribute__((ext_vector_type(8))) short short8;
typedef __attribute__((ext_vector_type(4))) float f32x4;

static inline int cdiv(int a, int b) { return (a + b - 1) / b; }

__device__ __forceinline__ unsigned short bf16_rtn(float v) {
    unsigned u = __float_as_uint(v);
    return (unsigned short)((u + 0x7fffu + ((u >> 16) & 1u)) >> 16);
}

// ---------------- CSR build ----------------

// Fused: deg init + int64/int32 dtype detect (one wave checks 64 odd words).
__global__ void csr_init(const unsigned int* __restrict__ ei, int* __restrict__ flag,
                         int* __restrict__ deg, int N) {
    int i = blockIdx.x * blockDim.x + threadIdx.x;
    if (i < N) deg[i] = 1;  // self-loop occupies slot 0
    if (blockIdx.x == 0 && threadIdx.x < 64) {
        int nz = (ei[2 * threadIdx.x + 1] != 0u) ? 1 : 0;
        unsigned long long b = __ballot(nz);
        if (threadIdx.x == 0) *flag = (b == 0ull) ? 1 : 0;
    }
}

// Histogram + record each edge's slot within its destination row.
__global__ void hist_kernel(const int* __restrict__ ei, int E, const int* __restrict__ flag,
                            int* __restrict__ deg, int* __restrict__ pos) {
    int e = blockIdx.x * blockDim.x + threadIdx.x;
    if (e >= E) return;
    int is64 = *flag;
    int d = is64 ? ei[2 * (E + e)] : ei[E + e];
    pos[e] = atomicAdd(&deg[d], 1);
}

__global__ void scan_blocks(const int* __restrict__ deg, int* __restrict__ rowptr,
                            int* __restrict__ partials, int N) {
    __shared__ int sdata[256];
    int t = threadIdx.x;
    int idx0 = blockIdx.x * SCAN_CHUNK + t * 4;
    int v[4]; int sum = 0;
    #pragma unroll
    for (int i = 0; i < 4; ++i) {
        int ii = idx0 + i;
        v[i] = (ii < N) ? deg[ii] : 0;
        sum += v[i];
    }
    sdata[t] = sum;
    __syncthreads();
    for (int off = 1; off < 256; off <<= 1) {
        int val = 0;
        if (t >= off) val = sdata[t - off];
        __syncthreads();
        if (t >= off) sdata[t] += val;
        __syncthreads();
    }
    int run = (t > 0) ? sdata[t - 1] : 0;
    #pragma unroll
    for (int i = 0; i < 4; ++i) {
        int ii = idx0 + i;
        if (ii < N) rowptr[ii] = run;
        run += v[i];
    }
    if (t == 255) partials[blockIdx.x] = sdata[255];
}

__global__ void scan_partials_k(int* __restrict__ partials, int NB) {
    __shared__ int sd[256];
    int t = threadIdx.x;
    sd[t] = (t < NB) ? partials[t] : 0;
    __syncthreads();
    for (int off = 1; off < 256; off <<= 1) {
        int val = 0;
        if (t >= off) val = sd[t - off];
        __syncthreads();
        if (t >= off) sd[t] += val;
        __syncthreads();
    }
    if (t < NB) partials[t] = (t > 0) ? sd[t - 1] : 0;
}

__global__ void add_offsets(int* __restrict__ rowptr, const int* __restrict__ partials,
                            int N, int Etot) {
    int i = blockIdx.x * blockDim.x + threadIdx.x;
    if (i < N) rowptr[i] += partials[i / SCAN_CHUNK];
    if (i == 0) rowptr[N] = Etot;
}

__global__ void fill_csr(const int* __restrict__ ei, int E, int N, const int* __restrict__ flag,
                         const int* __restrict__ rowptr, const int* __restrict__ pos,
                         int* __restrict__ col) {
    int i = blockIdx.x * blockDim.x + threadIdx.x;
    if (i >= E + N) return;
    if (i < E) {
        int is64 = *flag;
        int s = is64 ? ei[2 * i] : ei[i];
        int d = is64 ? ei[2 * (E + i)] : ei[E + i];
        col[rowptr[d] + pos[i]] = s;
    } else {
        int nn = i - E;
        col[rowptr[nn]] = nn;  // self-loop at slot 0
    }
}

// ---------------- weight pre-swizzle (hi bf16 only) ----------------
// Flat index: ((((l*2+h)*4+ct)*2+kc)*64+lane)*8+j -> W[k=kc*32+(lane>>4)*8+j][ct*16+(lane&15)]
__global__ void wprep_kernel(const float* __restrict__ Wl, const float* __restrict__ Wr,
                             unsigned short* __restrict__ Bh, int Lnum) {
    int t = blockIdx.x * blockDim.x + threadIdx.x;
    int total = Lnum * 2 * 4 * 2 * 64 * 8;
    if (t >= total) return;
    int j    = t & 7;
    int lane = (t >> 3) & 63;
    int kc   = (t >> 9) & 1;
    int ct   = (t >> 10) & 3;
    int h    = (t >> 12) & 1;
    int l    = t >> 13;
    const float* W = (h ? Wr : Wl) + (size_t)l * 4096;
    int k = kc * 32 + (lane >> 4) * 8 + j;
    int c = ct * 16 + (lane & 15);
    Bh[t] = bf16_rtn(W[k * 64 + c]);
}

// ---------------- transform: [XL|XR] = x @ [Wl|Wr] via MFMA, f32 input split in-register ----
// Wave = one 16-node group x one 64-col half (half 0 -> XL bf16, half 1 -> XR f32).
// XL uses x_hi only (below bf16 output precision); XR adds the x_lo correction term.
__global__ __launch_bounds__(256) void transform_mfma(
    const float* __restrict__ x, const unsigned short* __restrict__ Bh,
    unsigned short* __restrict__ XL, float* __restrict__ XR, int N) {
    int lane = threadIdx.x & 63;
    int wid = (blockIdx.x * blockDim.x + threadIdx.x) >> 6;
    int nw = (gridDim.x * blockDim.x) >> 6;
    int half = wid & 1;

    const short8* Bh8 = (const short8*)Bh;
    short8 bh[4][2];
    #pragma unroll
    for (int ct = 0; ct < 4; ++ct)
        #pragma unroll
        for (int kc = 0; kc < 2; ++kc)
            bh[ct][kc] = Bh8[((half * 4 + ct) * 2 + kc) * 64 + lane];

    int r16 = lane & 15, kq = lane >> 4;
    int ngroups = N >> 4;  // 100000/16 = 6250 exactly

    for (int gidx = wid >> 1; gidx < ngroups; gidx += (nw >> 1)) {
        int n0 = gidx << 4;
        const float4* row = (const float4*)(x + (size_t)(n0 + r16) * 64);
        float4 f0 = row[2 * kq], f1 = row[2 * kq + 1];      // k = 8kq..8kq+7
        float4 f2 = row[8 + 2 * kq], f3 = row[8 + 2 * kq + 1];  // k = 32+8kq..
        float fa[8] = {f0.x, f0.y, f0.z, f0.w, f1.x, f1.y, f1.z, f1.w};
        float fb[8] = {f2.x, f2.y, f2.z, f2.w, f3.x, f3.y, f3.z, f3.w};
        short8 ah0, ah1, al0, al1;
        #pragma unroll
        for (int j = 0; j < 8; ++j) {
            unsigned short h0 = bf16_rtn(fa[j]);
            unsigned short h1 = bf16_rtn(fb[j]);
            ah0[j] = (short)h0;
            ah1[j] = (short)h1;
            al0[j] = (short)bf16_rtn(fa[j] - __uint_as_float((unsigned)h0 << 16));
            al1[j] = (short)bf16_rtn(fb[j] - __uint_as_float((unsigned)h1 << 16));
        }

        f32x4 acc[4] = {};
        #pragma unroll
        for (int ct = 0; ct < 4; ++ct) {
            acc[ct] = __builtin_amdgcn_mfma_f32_16x16x32_bf16(ah0, bh[ct][0], acc[ct], 0, 0, 0);
            acc[ct] = __builtin_amdgcn_mfma_f32_16x16x32_bf16(ah1, bh[ct][1], acc[ct], 0, 0, 0);
        }
        if (half) {
            #pragma unroll
            for (int ct = 0; ct < 4; ++ct) {
                acc[ct] = __builtin_amdgcn_mfma_f32_16x16x32_bf16(al0, bh[ct][0], acc[ct], 0, 0, 0);
                acc[ct] = __builtin_amdgcn_mfma_f32_16x16x32_bf16(al1, bh[ct][1], acc[ct], 0, 0, 0);
            }
        }
        // C/D layout (m89-verified): col = lane&15, row = (lane>>4)*4 + reg
        if (half) {
            #pragma unroll
            for (int ct = 0; ct < 4; ++ct)
                #pragma unroll
                for (int r = 0; r < 4; ++r)
                    XR[(size_t)(n0 + kq * 4 + r) * 64 + ct * 16 + r16] = acc[ct][r];
        } else {
            #pragma unroll
            for (int ct = 0; ct < 4; ++ct)
                #pragma unroll
                for (int r = 0; r < 4; ++r)
                    XL[(size_t)(n0 + kq * 4 + r) * 64 + ct * 16 + r16] = bf16_rtn(acc[ct][r]);
        }
    }
}

// ---------------- gather: online-softmax attention + epilogue ----------------
// One wave per destination node; lane = (edge slot g = lane>>4) x (feature quad c = lane&15).
// 8 edges in flight per iteration (2 per subgroup), single paired softmax update.
__global__ __launch_bounds__(512) void gat_gather_kernel(
    const unsigned short* __restrict__ XL, const float* __restrict__ XR,
    const float* __restrict__ x_res,
    const int* __restrict__ rowptr, const int* __restrict__ col,
    const float* __restrict__ att, const float* __restrict__ bias,
    const float* __restrict__ gamma, const float* __restrict__ beta,
    float* __restrict__ x_out, int N) {
    int wid = (blockIdx.x * blockDim.x + threadIdx.x) >> 6;
    if (wid >= N) return;
    int lane = threadIdx.x & 63;
    int g = lane >> 4;
    int c = lane & 15;
    const int n = wid;

    float4 xr = ((const float4*)(XR + (size_t)n * 64))[c];
    float4 av = ((const float4*)att)[c];
    int start = rowptr[n], end = rowptr[n + 1];
    const ushort4* XL4 = (const ushort4*)XL;

    float m = -1e30f, s = 0.f;
    float o0 = 0.f, o1 = 0.f, o2 = 0.f, o3 = 0.f;

    for (int base = start; base < end; base += 64) {
        int rem = end - base;
        int chunk = rem < 64 ? rem : 64;
        int cidx = base + lane;
        int cl = col[cidx < end ? cidx : end - 1];
        int iters = (chunk + 7) >> 3;
        for (int t = 0; t < iters; ++t) {
            int ia = 8 * t + g;
            int ib = ia + 4;
            int sa = __shfl(cl, ia);
            int sb = __shfl(cl, ib);
            ushort4 ha = XL4[(size_t)sa * 16 + c];   // two independent loads in flight
            ushort4 hb = XL4[(size_t)sb * 16 + c];
            float va0 = __uint_as_float((unsigned)ha.x << 16);
            float va1 = __uint_as_float((unsigned)ha.y << 16);
            float va2 = __uint_as_float((unsigned)ha.z << 16);
            float va3 = __uint_as_float((unsigned)ha.w << 16);
            float vb0 = __uint_as_float((unsigned)hb.x << 16);
            float vb1 = __uint_as_float((unsigned)hb.y << 16);
            float vb2 = __uint_as_float((unsigned)hb.z << 16);
            float vb3 = __uint_as_float((unsigned)hb.w << 16);
            float ta0 = va0 + xr.x; ta0 = fmaxf(ta0, 0.2f * ta0);
            float ta1 = va1 + xr.y; ta1 = fmaxf(ta1, 0.2f * ta1);
            float ta2 = va2 + xr.z; ta2 = fmaxf(ta2, 0.2f * ta2);
            float ta3 = va3 + xr.w; ta3 = fmaxf(ta3, 0.2f * ta3);
            float tb0 = vb0 + xr.x; tb0 = fmaxf(tb0, 0.2f * tb0);
            float tb1 = vb1 + xr.y; tb1 = fmaxf(tb1, 0.2f * tb1);
            float tb2 = vb2 + xr.z; tb2 = fmaxf(tb2, 0.2f * tb2);
            float tb3 = vb3 + xr.w; tb3 = fmaxf(tb3, 0.2f * tb3);
            float wa = ta0 * av.x;
            wa = fmaf(ta1, av.y, wa);
            wa = fmaf(ta2, av.z, wa);
            wa = fmaf(ta3, av.w, wa);
            float wb = tb0 * av.x;
            wb = fmaf(tb1, av.y, wb);
            wb = fmaf(tb2, av.z, wb);
            wb = fmaf(tb3, av.w, wb);
            wa += __shfl_xor(wa, 1);   // 4-lane (per-head) reduce
            wa += __shfl_xor(wa, 2);
            wb += __shfl_xor(wb, 1);
            wb += __shfl_xor(wb, 2);
            wa = (ia < chunk) ? wa : -1e30f;
            wb = (ib < chunk) ? wb : -1e30f;
            float mn = fmaxf(fmaxf(m, wa), wb);
            float pa = __expf(wa - mn);
            float pb = __expf(wb - mn);
            float sc = __expf(m - mn);
            s = fmaf(s, sc, pa + pb);
            o0 = fmaf(o0, sc, fmaf(pa, va0, pb * vb0));
            o1 = fmaf(o1, sc, fmaf(pa, va1, pb * vb1));
            o2 = fmaf(o2, sc, fmaf(pa, va2, pb * vb2));
            o3 = fmaf(o3, sc, fmaf(pa, va3, pb * vb3));
            m = mn;
        }
    }

    // merge the 4 subgroup partials (finite sentinel => exp paths stay NaN-free)
    #pragma unroll
    for (int mask = 16; mask <= 32; mask <<= 1) {
        float m2 = __shfl_xor(m, mask);
        float s2 = __shfl_xor(s, mask);
        float q0 = __shfl_xor(o0, mask);
        float q1 = __shfl_xor(o1, mask);
        float q2 = __shfl_xor(o2, mask);
        float q3 = __shfl_xor(o3, mask);
        float mn = fmaxf(m, m2);
        float sa = __expf(m - mn), sb = __expf(m2 - mn);
        s = s * sa + s2 * sb;
        o0 = o0 * sa + q0 * sb;
        o1 = o1 * sa + q1 * sb;
        o2 = o2 * sa + q2 * sb;
        o3 = o3 * sa + q3 * sb;
        m = mn;
    }

    float inv = 1.f / s;
    float4 bi = ((const float4*)bias)[c];
    float4 rs = ((const float4*)(x_res + (size_t)n * 64))[c];
    float g0 = fmaf(o0, inv, bi.x + rs.x);
    float g1 = fmaf(o1, inv, bi.y + rs.y);
    float g2 = fmaf(o2, inv, bi.z + rs.z);
    float g3 = fmaf(o3, inv, bi.w + rs.w);

    // LayerNorm over 64 features (4 per lane x 16 lanes; subgroups hold identical copies)
    float loc = g0 + g1 + g2 + g3;
    #pragma unroll
    for (int mask = 1; mask < 16; mask <<= 1) loc += __shfl_xor(loc, mask);
    float mu = loc * (1.f / 64.f);
    float d0 = g0 - mu, d1 = g1 - mu, d2 = g2 - mu, d3 = g3 - mu;
    float vs = d0 * d0 + d1 * d1 + d2 * d2 + d3 * d3;
    #pragma unroll
    for (int mask = 1; mask < 16; mask <<= 1) vs += __shfl_xor(vs, mask);
    float rstd = rsqrtf(vs * (1.f / 64.f) + 1e-5f);
    float4 ga = ((const float4*)gamma)[c];
    float4 be = ((const float4*)beta)[c];
    float y0 = fmaf(d0 * rstd, ga.x, be.x);
    float y1 = fmaf(d1 * rstd, ga.y, be.y);
    float y2 = fmaf(d2 * rstd, ga.z, be.z);
    float y3 = fmaf(d3 * rstd, ga.w, be.w);

    const float k = 0.70710678118654752f;
    float z0 = 0.5f * y0 * (1.f + erff(y0 * k));
    float z1 = 0.5f * y1 * (1.f + erff(y1 * k));
    float z2 = 0.5f * y2 * (1.f + erff(y2 * k));
    float z3 = 0.5f * y3 * (1.f + erff(y3 * k));

    if (g == 0) {
        ((float4*)(x_out + (size_t)n * 64))[c] = make_float4(z0, z1, z2, z3);
    }
}

// ---------------- launch ----------------

extern "C" void kernel_launch(void* const* d_in, const int* in_sizes, int n_in,
                              void* d_out, int out_size, void* d_ws, size_t ws_size,
                              hipStream_t stream) {
    const float* x0    = (const float*)d_in[0];
    const int*   ei    = (const int*)d_in[1];
    const float* Wl    = (const float*)d_in[2];
    const float* Wr    = (const float*)d_in[3];
    const float* att   = (const float*)d_in[4];
    const float* bias  = (const float*)d_in[5];
    const float* gamma = (const float*)d_in[6];
    const float* beta  = (const float*)d_in[7];
    float* out = (float*)d_out;

    const int N = in_sizes[0] / 64;
    const int E = in_sizes[1] / 2;
    const int Lnum = in_sizes[2] / (64 * 64);
    const int Etot = E + N;

    char* ws = (char*)d_ws;
    size_t off = 0;
    auto alloc = [&](size_t bytes) {
        void* p = ws + off;
        off = (off + bytes + 255) & ~(size_t)255;
        return p;
    };
    unsigned short* XLb = (unsigned short*)alloc((size_t)N * 64 * 2);
    float* XR     = (float*)alloc((size_t)N * 64 * 4);
    float* XA     = (float*)alloc((size_t)N * 64 * 4);
    unsigned short* Bh = (unsigned short*)alloc((size_t)Lnum * 8192 * 2);
    int* rowptr   = (int*)alloc((size_t)(N + 1) * 4);
    int* deg      = (int*)alloc((size_t)N * 4);
    int* pos      = (int*)alloc((size_t)E * 4);
    int* partials = (int*)alloc(1024 * 4);
    int* flag     = (int*)alloc(256);
    int* col      = (int*)alloc((size_t)Etot * 4);

    // weight pre-swizzle + CSR build (graph static across layers)
    wprep_kernel<<<cdiv(Lnum * 8192, 256), 256, 0, stream>>>(Wl, Wr, Bh, Lnum);
    csr_init<<<cdiv(N, 256), 256, 0, stream>>>((const unsigned int*)ei, flag, deg, N);
    hist_kernel<<<cdiv(E, 256), 256, 0, stream>>>(ei, E, flag, deg, pos);
    int NB = cdiv(N, SCAN_CHUNK);
    scan_blocks<<<NB, 256, 0, stream>>>(deg, rowptr, partials, N);
    scan_partials_k<<<1, 256, 0, stream>>>(partials, NB);
    add_offsets<<<cdiv(N + 1, 256), 256, 0, stream>>>(rowptr, partials, N, Etot);
    fill_csr<<<cdiv(Etot, 256), 256, 0, stream>>>(ei, E, N, flag, rowptr, pos, col);

    const float* xcur = x0;
    for (int l = 0; l < Lnum; ++l) {
        transform_mfma<<<2048, 256, 0, stream>>>(
            xcur, Bh + (size_t)l * 8192, XLb, XR, N);
        float* xnext = (l == Lnum - 1) ? out : XA;
        gat_gather_kernel<<<cdiv(N * 64, 512), 512, 0, stream>>>(
            XLb, XR, xcur, rowptr, col,
            att + (size_t)l * 64, bias + (size_t)l * 64,
            gamma + (size_t)l * 64, beta + (size_t)l * 64,
            xnext, N);
        xcur = xnext;
    }
}